// Round 31
// baseline (49.924 us; speedup 1.0000x reference)
//
#include <hip/hip_runtime.h>

// AttentionConvFull: grouped 1x1 QKV + 5x5 per-channel local attention, FUSED.
// B=4, H=W=56, C=OC=256, G=8, Cg=32, K=5, pad=2.
//
// R31 = R28 phases, TWO TILES PER BLOCK (software pipeline).
// Pairing: batches bA=2s, bB=2s+1 with same (ti,tj,g) -> identical weights.
// Grid 784. Sequence:
//   stage wTs + xA -> b1 -> load 6 B-frags (regs; wTs dead -> qs alias)
//   -> b2 -> mfmaA (kvs,qs) -> relp -> b3 -> [stage xB (xs16 dead for A)
//   OVERLAPS attnA] -> b4 -> mfmaB -> b5 -> attnB.
// Gains: xB stage latency hidden under attnA's VALU phase; w-staging,
// B-frag loads, relp amortized 2x; 5 barriers/2 tiles vs 6.
// Risk (accepted): B-frags 24 regs live across attnA -> compiler may
// spill/restore once; amortized over 2 tiles.
//
// MFMA geometry (m89-verified): D[144x96] = A[144x32] x B[32x96];
// A frag: lane(row=lw&15, k=(lw>>4)*8+j); B frag: B[k][col]=wTs[col][k];
// D: col=lane&15, row=(lane>>4)*4+reg. 16x16x32_f16, 54 MFMA/tile.
// LDS: xs16 11.25K + wTs/qs 7.5K + kvs 18.6K = 38.4KB (4 blocks/CU).
// XP=40 (80B rows): A/B b128 reads 2-way conflict only (free).
//
// Register law (R1-R30): residual ~8-reg spill at cap 128 is distributed /
// irreducible (8 targeted diets failed); cap 256 -> demand 136 -> worse band
// (R26). Precision: f16 proj + bf16 k,v/rel/q = 2.34e-2; threshold 5.69e-2.

constexpr int TB = 4, TH = 56, TW = 56, TC = 256;
constexpr int G  = 8, CG = 32, PAD = 2;
constexpr int TILE = 8;
constexpr int HT = TILE + 2 * PAD;   // 12
constexpr int NT = TH / TILE;        // 7
constexpr int NPIX_HALO = HT * HT;   // 144
constexpr int XP = 40;               // padded row (halves) for xs16/wTs
constexpr int KP = 33;               // padded row (words) for kvs
constexpr int QP = 34;               // padded row (u16) for qs alias
constexpr float LOG2E = 1.44269504088896340736f;

typedef __fp16 half2_t __attribute__((ext_vector_type(2)));
typedef __fp16 half8   __attribute__((ext_vector_type(8)));
typedef float  f32x4   __attribute__((ext_vector_type(4)));

__device__ __forceinline__ unsigned h2u(half2_t h) {
    union { half2_t h; unsigned u; } cv; cv.h = h; return cv.u;
}
__device__ __forceinline__ unsigned packbf(float k, float v) {
    return ((__float_as_uint(k) + 0x8000u) >> 16) |
           ((__float_as_uint(v) + 0x8000u) & 0xffff0000u);
}
__device__ __forceinline__ unsigned short packq(float q) {
    return (unsigned short)((__float_as_uint(q) + 0x8000u) >> 16);
}

__global__ __launch_bounds__(256, 2)
void fused_attn_conv_kernel(const float* __restrict__ x,
                            const float* __restrict__ wq,
                            const float* __restrict__ wk,
                            const float* __restrict__ wv,
                            const float* __restrict__ rel,
                            const float* __restrict__ qemb,
                            float* __restrict__ out) {
    __shared__ __align__(16) __fp16 xs16[NPIX_HALO][XP];  // 11.25 KB
    __shared__ __align__(16) __fp16 wTs[3 * CG][XP];      // 7.5 KB (then qs)
    __shared__ unsigned kvs[NPIX_HALO][KP];               // 18.6 KB
    unsigned short (*qs)[QP] = (unsigned short(*)[QP])&wTs[0][0];  // alias

    const int bid = blockIdx.x;
    const int g   = bid & 7;
    const int r0  = bid >> 3;
    const int tj  = r0 % NT;
    const int ti  = (r0 / NT) % NT;
    const int s   = r0 / (NT * NT);      // 0..1
    const int bA  = 2 * s, bB = 2 * s + 1;

    const int t  = threadIdx.x;
    const int c  = t & 31;
    const int p0 = t >> 5;

    const int oc = g * CG + c;
    const int h0 = ti * TILE - PAD, w0 = tj * TILE - PAD;

    unsigned (*xsu)[XP / 2] = (unsigned(*)[XP / 2])xs16;

    // ---- stage x halo for batch b -> xs16 (f16 pairs, coalesced).
    auto stage_x = [&](int b) {
#pragma unroll 3
        for (int r = 0; r < 9; ++r) {
            const int f  = t + r * 256;
            const int px = f >> 4, pr = f & 15;
            const int hi = px / HT, hj = px % HT;
            const int gh = h0 + hi, gw = w0 + hj;
            unsigned val = 0u;
            if (gh >= 0 && gh < TH && gw >= 0 && gw < TW) {
                const float2 xv = *(const float2*)(x + (((size_t)b * TH + gh) * TW + gw) * TC
                                                     + g * CG + pr * 2);
                val = h2u(__builtin_amdgcn_cvt_pkrtz(xv.x, xv.y));
            }
            xsu[px][pr] = val;
        }
    };

    // ---- leg 0: stage weights + xA
    stage_x(bA);
    {
        unsigned (*wTu)[XP / 2] = (unsigned(*)[XP / 2])wTs;
        const float* wsrc[3] = {wq, wk, wv};
#pragma unroll
        for (int m = 0; m < 3; ++m) {
#pragma unroll
            for (int r = 0; r < 2; ++r) {
                const int f = t + r * 256;
                const int row = f >> 4, pr = f & 15;
                const float2 wv2 = *(const float2*)(wsrc[m] + ((size_t)(g * CG + row)) * CG
                                                            + pr * 2);
                wTu[m * CG + row][pr] = h2u(__builtin_amdgcn_cvt_pkrtz(wv2.x, wv2.y));
            }
        }
    }

    __syncthreads();   // b1: stage -> B-frag loads

    const int lw = t & 63, wvid = t >> 6;
    const int lcol = lw & 15;
    const int lko  = (lw >> 4) * 8;
    const f32x4 z4 = {0.f, 0.f, 0.f, 0.f};

    // B-frags in registers for BOTH tiles (wTs dead after these reads).
    const half8 bq0 = *(const half8*)&wTs[ 0 + lcol][lko];
    const half8 bq1 = *(const half8*)&wTs[16 + lcol][lko];
    const half8 bk0 = *(const half8*)&wTs[32 + lcol][lko];
    const half8 bk1 = *(const half8*)&wTs[48 + lcol][lko];
    const half8 bv0 = *(const half8*)&wTs[64 + lcol][lko];
    const half8 bv1 = *(const half8*)&wTs[80 + lcol][lko];
    const float qeL = qemb[g * CG + lcol];
    const float qeH = qemb[g * CG + lcol + 16];

    // ---- MFMA projection for the tile currently in xs16.
    auto mfma_tile = [&]() {
#pragma unroll 1
        for (int mt = wvid; mt < 9; mt += 4) {
            const half8 a = *(const half8*)&xs16[mt * 16 + lcol][lko];
            const f32x4 dk0 = __builtin_amdgcn_mfma_f32_16x16x32_f16(a, bk0, z4, 0, 0, 0);
            const f32x4 dk1 = __builtin_amdgcn_mfma_f32_16x16x32_f16(a, bk1, z4, 0, 0, 0);
            const f32x4 dv0 = __builtin_amdgcn_mfma_f32_16x16x32_f16(a, bv0, z4, 0, 0, 0);
            const f32x4 dv1 = __builtin_amdgcn_mfma_f32_16x16x32_f16(a, bv1, z4, 0, 0, 0);
            const int prow = mt * 16 + ((lw >> 4) << 2);
#pragma unroll
            for (int j = 0; j < 4; ++j) {
                const int px = prow + j;
                kvs[px][lcol]      = packbf(dk0[j], dv0[j]);
                kvs[px][lcol + 16] = packbf(dk1[j], dv1[j]);
            }
        }
#pragma unroll 1
        for (int mt = wvid; mt < 9; mt += 4) {
            const half8 a = *(const half8*)&xs16[mt * 16 + lcol][lko];
            const f32x4 dq0 = __builtin_amdgcn_mfma_f32_16x16x32_f16(a, bq0, z4, 0, 0, 0);
            const f32x4 dq1 = __builtin_amdgcn_mfma_f32_16x16x32_f16(a, bq1, z4, 0, 0, 0);
            const int prow = mt * 16 + ((lw >> 4) << 2);
#pragma unroll
            for (int j = 0; j < 4; ++j) {
                const int px = prow + j;
                const int hi2 = px / HT, hj2 = px % HT;
                if (hi2 >= PAD && hi2 < PAD + TILE && hj2 >= PAD && hj2 < PAD + TILE) {
                    const int qp = (hi2 - PAD) * TILE + (hj2 - PAD);
                    qs[qp][lcol]      = packq((dq0[j] + qeL) * LOG2E);
                    qs[qp][lcol + 16] = packq((dq1[j] + qeH) * LOG2E);
                }
            }
        }
    };

    // rel row -> 13 packed bf16 pairs (reused for both tiles)
    unsigned relp[13];
    {
        const float* rp = rel + (size_t)oc * 25;
#pragma unroll
        for (int i = 0; i < 12; ++i) {
            const unsigned lo = __float_as_uint(rp[2 * i])     + 0x8000u;
            const unsigned hi = __float_as_uint(rp[2 * i + 1]) + 0x8000u;
            relp[i] = (lo >> 16) | (hi & 0xffff0000u);
        }
        relp[12] = (__float_as_uint(rp[24]) + 0x8000u) >> 16;
    }

    // ---- attention for batch b (reads kvs + qs, writes out).
    auto attn_tile = [&](int b) {
        float s_[8], a_[8];
#pragma unroll
        for (int ii = 0; ii < 8; ++ii) { s_[ii] = 0.f; a_[ii] = 0.f; }
#pragma unroll
        for (int h = 0; h < HT; ++h) {
            float kr[5], vr[5];
#pragma unroll
            for (int j = 0; j < 5; ++j) {
                const unsigned u = kvs[h * HT + p0 + j][c];
                kr[j] = __uint_as_float(u << 16);
                vr[j] = __uint_as_float(u & 0xffff0000u);
            }
#pragma unroll
            for (int ii = 0; ii < 8; ++ii) {
                const int di = h - ii;
                if (di >= 0 && di < 5) {
                    const float qv =
                        __uint_as_float((unsigned)qs[ii * TILE + p0][c] << 16);
#pragma unroll
                    for (int j = 0; j < 5; ++j) {
                        const int idx = di * 5 + j;
                        const unsigned ru = relp[idx >> 1];
                        const float rl = __uint_as_float((idx & 1) ? (ru & 0xffff0000u)
                                                                   : (ru << 16));
                        const float e = __builtin_amdgcn_exp2f(qv * (kr[j] + rl));
                        s_[ii] += e;
                        a_[ii] = fmaf(e, vr[j], a_[ii]);
                    }
                }
            }
        }
#pragma unroll
        for (int ii = 0; ii < 8; ++ii) {
            const int gh = ti * TILE + ii, gw = tj * TILE + p0;
            out[(((size_t)b * TH + gh) * TW + gw) * TC + g * CG + c] =
                a_[ii] * __builtin_amdgcn_rcpf(s_[ii]);
        }
    };

    __syncthreads();   // b2: B-frags loaded -> qs alias safe

    mfma_tile();       // tile A -> kvs/qs

    __syncthreads();   // b3: mfmaA done -> attnA may read; xs16 dead

    stage_x(bB);       // overlaps attnA (xs16 not read by attn)
    attn_tile(bA);

    __syncthreads();   // b4: attnA done reading kvs/qs; xB staged

    mfma_tile();       // tile B -> kvs/qs

    __syncthreads();   // b5: mfmaB done

    attn_tile(bB);
}

extern "C" void kernel_launch(void* const* d_in, const int* in_sizes, int n_in,
                              void* d_out, int out_size, void* d_ws, size_t ws_size,
                              hipStream_t stream) {
    const float* x    = (const float*)d_in[0];
    const float* wq   = (const float*)d_in[1];
    const float* wk   = (const float*)d_in[2];
    const float* wv   = (const float*)d_in[3];
    const float* rel  = (const float*)d_in[4];
    const float* qemb = (const float*)d_in[5];
    float* out = (float*)d_out;

    const int nblocks = (TB / 2) * NT * NT * G;   // 2*7*7*8 = 784
    hipLaunchKernelGGL(fused_attn_conv_kernel, dim3(nblocks), dim3(256), 0, stream,
                       x, wq, wk, wv, rel, qemb, out);
}

// Round 32
// 38.092 us; speedup vs baseline: 1.3106x; 1.3106x over previous
//
#include <hip/hip_runtime.h>

// AttentionConvFull: grouped 1x1 QKV + 5x5 per-channel local attention, FUSED.
// B=4, H=W=56, C=OC=256, G=8, Cg=32, K=5, pad=2.
//
// R32 = R28 EXACTLY (champion, 38.1us) - reverting R31's two-tile pipeline
// (spilled 61MB, 49.9us: B-frags+relp live across attn = mass spill).
//
// Final structure:
//   Stage:   x halo -> xs16 (f16 pairs) + weights -> wTs (f16), coalesced.
//   MFMA:    D[144x96] = A[144x32] x B[32x96] via mfma_f32_16x16x32_f16,
//            54 MFMA/block; kv-pass then q-pass; k,v packed bf16x2 -> kvs;
//            q (bf16, *log2e) -> qs ALIASED onto dead wTs storage.
//   Phase C: row-streaming per-channel softmax attention; native exp2/rcp;
//            k,v,rel,q bf16-unpacked at use.
// LDS 38.4KB -> 4 blocks/CU. 3 barriers.
//
// Session ledger (31 rounds): scalar-VALU fused design plateaued 52-60us
// (VALU-bound, MfmaUtil 0); MFMA projection broke through to 38-41us.
// Residual ~8-reg spill at cap 128 (VGPR==128, WRITE ~23MB vs 12.5 logical)
// is DISTRIBUTED allocator pressure - 10 targeted interventions neutral or
// negative; cap-256 reveals demand 136 but the >128 band costs more (R26).
// Occupancy bands: <=64/<=128/<=256 by measured VGPR; launch_bounds 2nd arg
// does not cap residency (R20). Forced caps below demand spill 2-10x (R3-
// R15). Precision: f16 proj + bf16 k,v/rel/q = 2.34e-2; threshold 5.69e-2.

constexpr int TB = 4, TH = 56, TW = 56, TC = 256;
constexpr int G  = 8, CG = 32, PAD = 2;
constexpr int TILE = 8;
constexpr int HT = TILE + 2 * PAD;   // 12
constexpr int NT = TH / TILE;        // 7
constexpr int NPIX_HALO = HT * HT;   // 144
constexpr int XP = 40;               // padded row (halves) for xs16/wTs
constexpr int KP = 33;               // padded row (words) for kvs
constexpr int QP = 34;               // padded row (u16) for qs alias
constexpr float LOG2E = 1.44269504088896340736f;

typedef __fp16 half2_t __attribute__((ext_vector_type(2)));
typedef __fp16 half8   __attribute__((ext_vector_type(8)));
typedef float  f32x4   __attribute__((ext_vector_type(4)));

__device__ __forceinline__ unsigned h2u(half2_t h) {
    union { half2_t h; unsigned u; } cv; cv.h = h; return cv.u;
}
__device__ __forceinline__ unsigned packbf(float k, float v) {
    return ((__float_as_uint(k) + 0x8000u) >> 16) |
           ((__float_as_uint(v) + 0x8000u) & 0xffff0000u);
}
__device__ __forceinline__ unsigned short packq(float q) {
    return (unsigned short)((__float_as_uint(q) + 0x8000u) >> 16);
}

__global__ __launch_bounds__(256, 2)
void fused_attn_conv_kernel(const float* __restrict__ x,
                            const float* __restrict__ wq,
                            const float* __restrict__ wk,
                            const float* __restrict__ wv,
                            const float* __restrict__ rel,
                            const float* __restrict__ qemb,
                            float* __restrict__ out) {
    __shared__ __align__(16) __fp16 xs16[NPIX_HALO][XP];  // 11.25 KB
    __shared__ __align__(16) __fp16 wTs[3 * CG][XP];      // 7.5 KB (then qs)
    __shared__ unsigned kvs[NPIX_HALO][KP];               // 18.6 KB
    // qs alias: valid only AFTER barrier2 (B-frags already in registers)
    unsigned short (*qs)[QP] = (unsigned short(*)[QP])&wTs[0][0];  // 4.25 KB

    const int bid  = blockIdx.x;
    const int g    = bid & 7;
    const int tile = bid >> 3;
    const int tj   = tile % NT;
    const int ti   = (tile / NT) % NT;
    const int b    = tile / (NT * NT);

    const int t  = threadIdx.x;
    const int c  = t & 31;
    const int p0 = t >> 5;

    const int oc = g * CG + c;           // global out-channel (phase C)
    const int h0 = ti * TILE - PAD, w0 = tj * TILE - PAD;

    // ---- Stage x halo -> xs16 (f16 pairs; 2304 u32, 9/thread, coalesced).
    unsigned (*xsu)[XP / 2] = (unsigned(*)[XP / 2])xs16;
#pragma unroll 3
    for (int r = 0; r < 9; ++r) {
        const int f  = t + r * 256;          // 0..2303
        const int px = f >> 4, pr = f & 15;  // 16 channel-pairs per pixel
        const int hi = px / HT, hj = px % HT;
        const int gh = h0 + hi, gw = w0 + hj;
        unsigned val = 0u;
        if (gh >= 0 && gh < TH && gw >= 0 && gw < TW) {
            const float2 xv = *(const float2*)(x + (((size_t)b * TH + gh) * TW + gw) * TC
                                                 + g * CG + pr * 2);
            val = h2u(__builtin_amdgcn_cvt_pkrtz(xv.x, xv.y));
        }
        xsu[px][pr] = val;
    }

    // ---- Stage weights -> wTs (rows 0-31 wq, 32-63 wk, 64-95 wv).
    {
        unsigned (*wTu)[XP / 2] = (unsigned(*)[XP / 2])wTs;
        const float* wsrc[3] = {wq, wk, wv};
#pragma unroll
        for (int m = 0; m < 3; ++m) {
#pragma unroll
            for (int r = 0; r < 2; ++r) {
                const int f = t + r * 256;           // 0..511 float2 idx
                const int row = f >> 4, pr = f & 15; // row=oc 0..31
                const float2 wv2 = *(const float2*)(wsrc[m] + ((size_t)(g * CG + row)) * CG
                                                            + pr * 2);
                wTu[m * CG + row][pr] = h2u(__builtin_amdgcn_cvt_pkrtz(wv2.x, wv2.y));
            }
        }
    }

    __syncthreads();   // barrier1: stage -> B-frag loads

    const int wvid = t >> 6, lw = t & 63;
    const int lcol = lw & 15;
    const int lko  = (lw >> 4) * 8;
    const f32x4 z4 = {0.f, 0.f, 0.f, 0.f};

    // ---- Hoist ALL 6 B-frags (wTs dead afterwards; qs may alias it).
    const half8 bq0 = *(const half8*)&wTs[ 0 + lcol][lko];
    const half8 bq1 = *(const half8*)&wTs[16 + lcol][lko];
    const half8 bk0 = *(const half8*)&wTs[32 + lcol][lko];
    const half8 bk1 = *(const half8*)&wTs[48 + lcol][lko];
    const half8 bv0 = *(const half8*)&wTs[64 + lcol][lko];
    const half8 bv1 = *(const half8*)&wTs[80 + lcol][lko];
    const float qeL = qemb[g * CG + lcol];
    const float qeH = qemb[g * CG + lcol + 16];

    __syncthreads();   // barrier2: all B-frags loaded -> qs alias is safe

    // ---- MFMA kv-pass: 4 D live.
#pragma unroll 1
    for (int mt = wvid; mt < 9; mt += 4) {        // waves: 3/2/2/2 M-tiles
        const half8 a = *(const half8*)&xs16[mt * 16 + lcol][lko];
        const f32x4 dk0 = __builtin_amdgcn_mfma_f32_16x16x32_f16(a, bk0, z4, 0, 0, 0);
        const f32x4 dk1 = __builtin_amdgcn_mfma_f32_16x16x32_f16(a, bk1, z4, 0, 0, 0);
        const f32x4 dv0 = __builtin_amdgcn_mfma_f32_16x16x32_f16(a, bv0, z4, 0, 0, 0);
        const f32x4 dv1 = __builtin_amdgcn_mfma_f32_16x16x32_f16(a, bv1, z4, 0, 0, 0);
        const int prow = mt * 16 + ((lw >> 4) << 2);
#pragma unroll
        for (int j = 0; j < 4; ++j) {
            const int px = prow + j;
            kvs[px][lcol]      = packbf(dk0[j], dv0[j]);
            kvs[px][lcol + 16] = packbf(dk1[j], dv1[j]);
        }
    }

    // ---- MFMA q-pass: 2 D live; q (bf16, *log2e) -> qs (aliased on wTs).
#pragma unroll 1
    for (int mt = wvid; mt < 9; mt += 4) {
        const half8 a = *(const half8*)&xs16[mt * 16 + lcol][lko];
        const f32x4 dq0 = __builtin_amdgcn_mfma_f32_16x16x32_f16(a, bq0, z4, 0, 0, 0);
        const f32x4 dq1 = __builtin_amdgcn_mfma_f32_16x16x32_f16(a, bq1, z4, 0, 0, 0);
        const int prow = mt * 16 + ((lw >> 4) << 2);
#pragma unroll
        for (int j = 0; j < 4; ++j) {
            const int px = prow + j;
            const int hi2 = px / HT, hj2 = px % HT;
            if (hi2 >= PAD && hi2 < PAD + TILE && hj2 >= PAD && hj2 < PAD + TILE) {
                const int qp = (hi2 - PAD) * TILE + (hj2 - PAD);
                qs[qp][lcol]      = packq((dq0[j] + qeL) * LOG2E);
                qs[qp][lcol + 16] = packq((dq1[j] + qeH) * LOG2E);
            }
        }
    }

    // rel row -> 13 packed bf16 pairs (even idx = low half, odd = high half)
    unsigned relp[13];
    {
        const float* rp = rel + (size_t)oc * 25;
#pragma unroll
        for (int i = 0; i < 12; ++i) {
            const unsigned lo = __float_as_uint(rp[2 * i])     + 0x8000u;
            const unsigned hi = __float_as_uint(rp[2 * i + 1]) + 0x8000u;
            relp[i] = (lo >> 16) | (hi & 0xffff0000u);
        }
        relp[12] = (__float_as_uint(rp[24]) + 0x8000u) >> 16;
    }

    __syncthreads();   // barrier3: MFMA -> phase C

    // q (bf16, already *log2e) for this thread's 8 column pixels
    float qreg[8];
#pragma unroll
    for (int ii = 0; ii < 8; ++ii)
        qreg[ii] = __uint_as_float((unsigned)qs[ii * TILE + p0][c] << 16);

    // ---- Phase C: monolithic row-streaming attention (champion structure).
    float s_[8], a_[8];
#pragma unroll
    for (int ii = 0; ii < 8; ++ii) { s_[ii] = 0.f; a_[ii] = 0.f; }

#pragma unroll
    for (int h = 0; h < HT; ++h) {
        float kr[5], vr[5];
#pragma unroll
        for (int j = 0; j < 5; ++j) {
            const unsigned u = kvs[h * HT + p0 + j][c];
            kr[j] = __uint_as_float(u << 16);          // bf16 k -> f32
            vr[j] = __uint_as_float(u & 0xffff0000u);  // bf16 v -> f32
        }
#pragma unroll
        for (int ii = 0; ii < 8; ++ii) {
            const int di = h - ii;               // compile-time after unroll
            if (di >= 0 && di < 5) {
                const float qv = qreg[ii];
#pragma unroll
                for (int j = 0; j < 5; ++j) {
                    const int idx = di * 5 + j;  // compile-time
                    const unsigned ru = relp[idx >> 1];
                    const float rl = __uint_as_float((idx & 1) ? (ru & 0xffff0000u)
                                                               : (ru << 16));
                    const float e = __builtin_amdgcn_exp2f(qv * (kr[j] + rl));
                    s_[ii] += e;
                    a_[ii] = fmaf(e, vr[j], a_[ii]);
                }
            }
        }
    }

#pragma unroll
    for (int ii = 0; ii < 8; ++ii) {
        const int gh = ti * TILE + ii, gw = tj * TILE + p0;
        out[(((size_t)b * TH + gh) * TW + gw) * TC + g * CG + c] =
            a_[ii] * __builtin_amdgcn_rcpf(s_[ii]);
    }
}

extern "C" void kernel_launch(void* const* d_in, const int* in_sizes, int n_in,
                              void* d_out, int out_size, void* d_ws, size_t ws_size,
                              hipStream_t stream) {
    const float* x    = (const float*)d_in[0];
    const float* wq   = (const float*)d_in[1];
    const float* wk   = (const float*)d_in[2];
    const float* wv   = (const float*)d_in[3];
    const float* rel  = (const float*)d_in[4];
    const float* qemb = (const float*)d_in[5];
    float* out = (float*)d_out;

    const int nblocks = TB * NT * NT * G;   // 4*7*7*8 = 1568
    hipLaunchKernelGGL(fused_attn_conv_kernel, dim3(nblocks), dim3(256), 0, stream,
                       x, wq, wk, wv, rel, qemb, out);
}